// Round 2
// baseline (566.088 us; speedup 1.0000x reference)
//
#include <hip/hip_runtime.h>

#define B_  32
#define TK_ 8192
#define H_  256
#define SR  32    // subtile rows
#define NS  8     // subtiles per block
#define NBX 32    // blocks along t (NBX*NS*SR = 8192)

typedef __bf16 bf16_t;
typedef __bf16 bf16x4 __attribute__((ext_vector_type(4)));
typedef __bf16 bf16x8 __attribute__((ext_vector_type(8)));
typedef float  floatx4 __attribute__((ext_vector_type(4)));

__device__ __forceinline__ float tanh_fast(float x) {
    // tanh(x) = 1 - 2/(1+e^{2x});  e^{2x} = exp2(2*log2(e)*x)
    float e = __builtin_amdgcn_exp2f(x * 2.885390081777927f);
    return 1.0f - 2.0f * __builtin_amdgcn_rcpf(e + 1.0f);
}

// ---------------- prep: convert We->bf16, compute dec_fea ---------------------
__global__ void prep_kernel(const float* __restrict__ s_t_hat,
                            const float* __restrict__ We,
                            const float* __restrict__ Wd,
                            const float* __restrict__ bd,
                            bf16_t* __restrict__ We_bf,
                            float* __restrict__ dec_ws) {
    int tid = threadIdx.x, blk = blockIdx.x;
    int gid = blk * 256 + tid;              // grid = 256 blocks -> 65536 threads
    We_bf[gid] = (bf16_t)We[gid];           // H*H = 65536 exactly

    if (blk >= 32 && blk < 160) {           // 32768 threads: 4 per (b,i)
        int idx  = (blk - 32) * 256 + tid;
        int pair = idx >> 2, q = idx & 3;
        int b = pair >> 8, i = pair & 255;
        const float4* sp = (const float4*)(s_t_hat + b * 2 * H_ + q * 128);
        const float4* wp = (const float4*)(Wd + (size_t)i * 2 * H_ + q * 128);
        float sum = 0.f;
        #pragma unroll 8
        for (int ii = 0; ii < 32; ++ii) {
            float4 a = sp[ii], w = wp[ii];
            sum += a.x * w.x + a.y * w.y + a.z * w.z + a.w * w.w;
        }
        sum += __shfl_xor(sum, 1, 64);
        sum += __shfl_xor(sum, 2, 64);
        if (q == 0) dec_ws[pair] = sum + bd[i];
    }
}

// ---------------- main fused pass: pipelined 32-row subtiles ------------------
__global__ __launch_bounds__(256, 4) void attn_main(
    const float* __restrict__ enc,
    const float* __restrict__ mask,
    const float* __restrict__ cov,
    const float* __restrict__ wc,
    const float* __restrict__ v,
    const bf16_t* __restrict__ We_bf,
    const float* __restrict__ dec_ws,
    float* __restrict__ ctx_part,   // [B][NBX][H]
    float* __restrict__ D_part,     // [B][NBX]
    float* __restrict__ attn_out) {

    __shared__ __align__(16) bf16_t As[2][SR * 264];   // ping-pong, 33792 B
    __shared__ float sp[4][SR];                        // per-wave score partials
    __shared__ float ctxp[4][256];                     // final ctx reduce

    const int tid  = threadIdx.x;
    const int b    = blockIdx.y;
    const int xb   = blockIdx.x;
    const int lane = tid & 63, w = tid >> 6;
    const int l15  = lane & 15, l4 = lane >> 4;
    const int t0b  = xb * (NS * SR);

    // B-side per-thread constants (L2-resident, no LDS staging needed)
    const int wbase = w * 64;
    float decv[4], wcv[4], vv[4];
    #pragma unroll
    for (int ni = 0; ni < 4; ++ni) {
        int g = wbase + ni * 16 + l15;
        decv[ni] = dec_ws[b * H_ + g];
        wcv[ni]  = wc[g];
        vv[ni]   = v[g];
    }

    const float* encb = enc + ((size_t)b * TK_ + t0b) * H_;
    const int colh = lane * 4;

    // prologue: stage subtile 0 into buffer 0
    #pragma unroll
    for (int it = 0; it < 8; ++it) {
        int row = it * 4 + w;
        float4 f = *(const float4*)(encb + (size_t)row * H_ + colh);
        bf16x4 q; q[0]=(bf16_t)f.x; q[1]=(bf16_t)f.y; q[2]=(bf16_t)f.z; q[3]=(bf16_t)f.w;
        *(bf16x4*)(&As[0][row * 264 + colh]) = q;
    }
    __syncthreads();

    float c0=0.f, c1=0.f, c2=0.f, c3=0.f;   // ctx acc: rows w*8..w*8+7, h=colh..+3
    float d_tot = 0.f;
    int p = 0;

    for (int s = 0; s < NS; ++s) {
        const int tg0 = t0b + s * SR;

        // A: issue next subtile's global loads (latency hides under B/C/D/E)
        float4 hold[8];
        if (s < NS - 1) {
            const float* nb = encb + (size_t)(s + 1) * SR * H_;
            #pragma unroll
            for (int it = 0; it < 8; ++it) {
                int row = it * 4 + w;
                hold[it] = *(const float4*)(nb + (size_t)row * H_ + colh);
            }
        }

        // B: GEMM on As[p] — wave w covers g in [w*64, w*64+64)
        floatx4 acc[2][4];
        #pragma unroll
        for (int mi = 0; mi < 2; ++mi)
            #pragma unroll
            for (int ni = 0; ni < 4; ++ni)
                acc[mi][ni] = (floatx4){0.f, 0.f, 0.f, 0.f};

        #pragma unroll
        for (int ks = 0; ks < 8; ++ks) {
            const int k = ks * 32 + l4 * 8;
            bf16x8 a0 = *(const bf16x8*)(&As[p][(     l15) * 264 + k]);
            bf16x8 a1 = *(const bf16x8*)(&As[p][(16 + l15) * 264 + k]);
            bf16x8 bq[4];
            #pragma unroll
            for (int ni = 0; ni < 4; ++ni)
                bq[ni] = *(const bf16x8*)(We_bf + (size_t)(wbase + ni * 16 + l15) * H_ + k);
            #pragma unroll
            for (int ni = 0; ni < 4; ++ni) {
                acc[0][ni] = __builtin_amdgcn_mfma_f32_16x16x32_bf16(a0, bq[ni], acc[0][ni], 0, 0, 0);
                acc[1][ni] = __builtin_amdgcn_mfma_f32_16x16x32_bf16(a1, bq[ni], acc[1][ni], 0, 0, 0);
            }
        }

        // C: scores. C-layout: col(g)=lane&15, row(t)=(lane>>4)*4+reg
        #pragma unroll
        for (int mi = 0; mi < 2; ++mi) {
            #pragma unroll
            for (int r = 0; r < 4; ++r) {
                int tl = mi * 16 + l4 * 4 + r;
                float cv = cov[(size_t)b * TK_ + tg0 + tl];
                float ssum = 0.f;
                #pragma unroll
                for (int ni = 0; ni < 4; ++ni) {
                    float af = acc[mi][ni][r] + decv[ni] + cv * wcv[ni];
                    ssum += tanh_fast(af) * vv[ni];
                }
                ssum += __shfl_xor(ssum, 1, 64);
                ssum += __shfl_xor(ssum, 2, 64);
                ssum += __shfl_xor(ssum, 4, 64);
                ssum += __shfl_xor(ssum, 8, 64);
                if (l15 == 0) sp[w][tl] = ssum;
            }
        }
        __syncthreads();   // sp visible; all waves done reading As[p] via GEMM

        // D: wave0 writes unnormalized attn + accumulates denominator
        if (w == 0) {
            float wv = 0.f;
            if (lane < SR) {
                float sc = sp[0][lane] + sp[1][lane] + sp[2][lane] + sp[3][lane];
                wv = __builtin_amdgcn_exp2f(sc * 1.4426950408889634f)
                     * mask[(size_t)b * TK_ + tg0 + lane];
                attn_out[(size_t)b * TK_ + tg0 + lane] = wv;
            }
            float d = wv;
            d += __shfl_xor(d, 1, 64);  d += __shfl_xor(d, 2, 64);
            d += __shfl_xor(d, 4, 64);  d += __shfl_xor(d, 8, 64);
            d += __shfl_xor(d, 16, 64); d += __shfl_xor(d, 32, 64);
            d_tot += d;
        }

        // E: ctx accumulate in registers (wave w owns rows w*8..w*8+7)
        #pragma unroll
        for (int j = 0; j < 8; ++j) {
            int t = w * 8 + j;
            float sc = sp[0][t] + sp[1][t] + sp[2][t] + sp[3][t];
            float wv = __builtin_amdgcn_exp2f(sc * 1.4426950408889634f)
                       * mask[(size_t)b * TK_ + tg0 + t];
            bf16x4 q = *(const bf16x4*)(&As[p][t * 264 + colh]);
            c0 += wv * (float)q[0];
            c1 += wv * (float)q[1];
            c2 += wv * (float)q[2];
            c3 += wv * (float)q[3];
        }

        // F: convert + write held regs into the other buffer
        if (s < NS - 1) {
            #pragma unroll
            for (int it = 0; it < 8; ++it) {
                int row = it * 4 + w;
                float4 f = hold[it];
                bf16x4 q; q[0]=(bf16_t)f.x; q[1]=(bf16_t)f.y; q[2]=(bf16_t)f.z; q[3]=(bf16_t)f.w;
                *(bf16x4*)(&As[p ^ 1][row * 264 + colh]) = q;
            }
        }
        __syncthreads();   // buffer p^1 staged; sp free for rewrite
        p ^= 1;
    }

    // final ctx cross-wave reduce (4 partial vectors of 256)
    *(float4*)(&ctxp[w][colh]) = (float4){c0, c1, c2, c3};
    __syncthreads();
    float sctx = ctxp[0][tid] + ctxp[1][tid] + ctxp[2][tid] + ctxp[3][tid];
    ctx_part[((size_t)b * NBX + xb) * H_ + tid] = sctx;

    if (w == 0 && lane == 0) D_part[b * NBX + xb] = d_tot;
}

// ---------------- finalize: reduce partials, write attn / new_cov / c_t ------
__global__ void finalize_kernel(const float* __restrict__ cov,
                                const float* __restrict__ ctx_part,
                                const float* __restrict__ D_part,
                                float* __restrict__ out) {
    int b = blockIdx.y, chunk = blockIdx.x, tid = threadIdx.x;
    int lane = tid & 63;

    // every wave redundantly reduces the 32 denominator partials (no barrier)
    float dv = (lane < NBX) ? D_part[b * NBX + lane] : 0.f;
    dv += __shfl_xor(dv, 1, 64);  dv += __shfl_xor(dv, 2, 64);
    dv += __shfl_xor(dv, 4, 64);  dv += __shfl_xor(dv, 8, 64);
    dv += __shfl_xor(dv, 16, 64); dv += __shfl_xor(dv, 32, 64);
    float invD = 1.0f / dv;

    int idx = chunk * 256 + tid;
    size_t gi = (size_t)b * TK_ + idx;
    float* attn = out + 8192;
    float* ncov = out + 8192 + (size_t)B_ * TK_;
    float a = attn[gi] * invD;
    attn[gi] = a;
    float nc = cov[gi] + a;
    ncov[gi] = fminf(fmaxf(nc, 0.f), 1.f);

    if (chunk == 0) {
        const float* cp = ctx_part + (size_t)b * NBX * H_ + tid;
        float s = 0.f;
        #pragma unroll
        for (int x = 0; x < NBX; ++x) s += cp[(size_t)x * H_];
        out[b * 256 + tid] = s * invD;
    }
}

extern "C" void kernel_launch(void* const* d_in, const int* in_sizes, int n_in,
                              void* d_out, int out_size, void* d_ws, size_t ws_size,
                              hipStream_t stream) {
    const float* s_t_hat = (const float*)d_in[0];
    const float* enc     = (const float*)d_in[1];
    const float* mask    = (const float*)d_in[2];
    const float* cov     = (const float*)d_in[3];
    // d_in[4] = attn_dist_node_to_token: unused by reference
    const float* We      = (const float*)d_in[5];
    const float* Wd      = (const float*)d_in[6];
    const float* bd      = (const float*)d_in[7];
    const float* wc      = (const float*)d_in[8];
    const float* v       = (const float*)d_in[9];
    float* out = (float*)d_out;

    char* ws = (char*)d_ws;
    bf16_t* We_bf    = (bf16_t*)ws;                          // 131072 B
    float*  dec_ws   = (float*)(ws + 131072);                // 32768 B
    float*  D_part   = (float*)(ws + 131072 + 32768);        // 32*32*4 = 4096 B
    float*  ctx_part = (float*)(ws + 131072 + 32768 + 4096); // 32*32*256*4 = 1 MiB

    prep_kernel<<<256, 256, 0, stream>>>(s_t_hat, We, Wd, bd, We_bf, dec_ws);
    attn_main<<<dim3(NBX, 32), 256, 0, stream>>>(enc, mask, cov, wc, v, We_bf,
                                                 dec_ws, ctx_part, D_part, out + 8192);
    finalize_kernel<<<dim3(32, 32), 256, 0, stream>>>(cov, ctx_part, D_part, out);
}

// Round 3
// 550.928 us; speedup vs baseline: 1.0275x; 1.0275x over previous
//
#include <hip/hip_runtime.h>

#define B_  32
#define TK_ 8192
#define H_  256
#define SR  32    // subtile rows
#define NS  8     // subtiles per block
#define NBX 32    // blocks along t (NBX*NS*SR = 8192)

typedef __bf16 bf16_t;
typedef __bf16 bf16x4 __attribute__((ext_vector_type(4)));
typedef __bf16 bf16x8 __attribute__((ext_vector_type(8)));
typedef float  floatx4 __attribute__((ext_vector_type(4)));

__device__ __forceinline__ float tanh_fast(float x) {
    // tanh(x) = 1 - 2/(1+e^{2x});  e^{2x} = exp2(2*log2(e)*x)
    float e = __builtin_amdgcn_exp2f(x * 2.885390081777927f);
    return 1.0f - 2.0f * __builtin_amdgcn_rcpf(e + 1.0f);
}

// ---------------- prep: convert We->bf16, compute dec_fea ---------------------
__global__ void prep_kernel(const float* __restrict__ s_t_hat,
                            const float* __restrict__ We,
                            const float* __restrict__ Wd,
                            const float* __restrict__ bd,
                            bf16_t* __restrict__ We_bf,
                            float* __restrict__ dec_ws) {
    int tid = threadIdx.x, blk = blockIdx.x;
    int gid = blk * 256 + tid;              // grid = 256 blocks -> 65536 threads
    We_bf[gid] = (bf16_t)We[gid];           // H*H = 65536 exactly

    if (blk >= 32 && blk < 160) {           // 32768 threads: 4 per (b,i)
        int idx  = (blk - 32) * 256 + tid;
        int pair = idx >> 2, q = idx & 3;
        int b = pair >> 8, i = pair & 255;
        const float4* sp = (const float4*)(s_t_hat + b * 2 * H_ + q * 128);
        const float4* wp = (const float4*)(Wd + (size_t)i * 2 * H_ + q * 128);
        float sum = 0.f;
        #pragma unroll 8
        for (int ii = 0; ii < 32; ++ii) {
            float4 a = sp[ii], w = wp[ii];
            sum += a.x * w.x + a.y * w.y + a.z * w.z + a.w * w.w;
        }
        sum += __shfl_xor(sum, 1, 64);
        sum += __shfl_xor(sum, 2, 64);
        if (q == 0) dec_ws[pair] = sum + bd[i];
    }
}

// ---------------- main fused pass: pipelined 32-row subtiles ------------------
// Prefetch is split into two 16-row halves held in only 4 float4 regs to stay
// under the 128-reg/wave budget for 4 blocks/CU (round-2 spilled 32 hold regs
// to scratch: 211 MB of extra HBM writes).
__global__ __launch_bounds__(256, 4) void attn_main(
    const float* __restrict__ enc,
    const float* __restrict__ mask,
    const float* __restrict__ cov,
    const float* __restrict__ wc,
    const float* __restrict__ v,
    const bf16_t* __restrict__ We_bf,
    const float* __restrict__ dec_ws,
    float* __restrict__ ctx_part,   // [B][NBX][H]
    float* __restrict__ D_part,     // [B][NBX]
    float* __restrict__ attn_out) {

    __shared__ __align__(16) bf16_t As[2][SR * 264];   // ping-pong, 33792 B
    __shared__ float sp[4][SR];                        // per-wave score partials
    __shared__ float ctxp[4][256];                     // final ctx reduce
    __shared__ float cov_s[256], mask_s[256];          // whole-block cov/mask

    const int tid  = threadIdx.x;
    const int b    = blockIdx.y;
    const int xb   = blockIdx.x;
    const int lane = tid & 63, w = tid >> 6;
    const int l15  = lane & 15, l4 = lane >> 4;
    const int t0b  = xb * (NS * SR);

    // B-side per-thread constants (L2-resident)
    const int wbase = w * 64;
    float decv[4], wcv[4], vv[4];
    #pragma unroll
    for (int ni = 0; ni < 4; ++ni) {
        int g = wbase + ni * 16 + l15;
        decv[ni] = dec_ws[b * H_ + g];
        wcv[ni]  = wc[g];
        vv[ni]   = v[g];
    }

    const float* encb = enc + ((size_t)b * TK_ + t0b) * H_;
    const int colh = lane * 4;

    // prologue: cov/mask for all 256 rows of this block + stage subtile 0
    cov_s[tid]  = cov[(size_t)b * TK_ + t0b + tid];
    mask_s[tid] = mask[(size_t)b * TK_ + t0b + tid];
    #pragma unroll
    for (int it = 0; it < 8; ++it) {
        int row = it * 4 + w;
        float4 f = *(const float4*)(encb + (size_t)row * H_ + colh);
        bf16x4 q; q[0]=(bf16_t)f.x; q[1]=(bf16_t)f.y; q[2]=(bf16_t)f.z; q[3]=(bf16_t)f.w;
        *(bf16x4*)(&As[0][row * 264 + colh]) = q;
    }
    __syncthreads();

    float c0=0.f, c1=0.f, c2=0.f, c3=0.f;   // ctx acc: rows w*8..w*8+7, h=colh..+3
    float d_tot = 0.f;
    int p = 0;

    for (int s = 0; s < NS; ++s) {
        const int tl0 = s * SR;                 // block-local row base
        const float* nb = encb + (size_t)(s + 1) * SR * H_;

        // A: issue first half of next subtile (rows 0..15) — lands during GEMM
        float4 hold[4];
        if (s < NS - 1) {
            #pragma unroll
            for (int it = 0; it < 4; ++it)
                hold[it] = *(const float4*)(nb + (size_t)(it * 4 + w) * H_ + colh);
        }

        // B: GEMM on As[p] — wave w covers g in [w*64, w*64+64)
        floatx4 acc[2][4];
        #pragma unroll
        for (int mi = 0; mi < 2; ++mi)
            #pragma unroll
            for (int ni = 0; ni < 4; ++ni)
                acc[mi][ni] = (floatx4){0.f, 0.f, 0.f, 0.f};

        #pragma unroll
        for (int ks = 0; ks < 8; ++ks) {
            const int k = ks * 32 + l4 * 8;
            bf16x8 a0 = *(const bf16x8*)(&As[p][(     l15) * 264 + k]);
            bf16x8 a1 = *(const bf16x8*)(&As[p][(16 + l15) * 264 + k]);
            bf16x8 bq[4];
            #pragma unroll
            for (int ni = 0; ni < 4; ++ni)
                bq[ni] = *(const bf16x8*)(We_bf + (size_t)(wbase + ni * 16 + l15) * H_ + k);
            #pragma unroll
            for (int ni = 0; ni < 4; ++ni) {
                acc[0][ni] = __builtin_amdgcn_mfma_f32_16x16x32_bf16(a0, bq[ni], acc[0][ni], 0, 0, 0);
                acc[1][ni] = __builtin_amdgcn_mfma_f32_16x16x32_bf16(a1, bq[ni], acc[1][ni], 0, 0, 0);
            }
        }

        // F1: write half 1 into other buffer; issue half 2 (reuses hold regs)
        if (s < NS - 1) {
            #pragma unroll
            for (int it = 0; it < 4; ++it) {
                float4 f = hold[it];
                bf16x4 q; q[0]=(bf16_t)f.x; q[1]=(bf16_t)f.y; q[2]=(bf16_t)f.z; q[3]=(bf16_t)f.w;
                *(bf16x4*)(&As[p ^ 1][(it * 4 + w) * 264 + colh]) = q;
            }
            #pragma unroll
            for (int it = 0; it < 4; ++it)
                hold[it] = *(const float4*)(nb + (size_t)(16 + it * 4 + w) * H_ + colh);
        }

        // C: scores. C-layout: col(g)=lane&15, row(t)=(lane>>4)*4+reg
        #pragma unroll
        for (int mi = 0; mi < 2; ++mi) {
            #pragma unroll
            for (int r = 0; r < 4; ++r) {
                int tl = mi * 16 + l4 * 4 + r;
                float cv = cov_s[tl0 + tl];
                float ssum = 0.f;
                #pragma unroll
                for (int ni = 0; ni < 4; ++ni) {
                    float af = acc[mi][ni][r] + decv[ni] + cv * wcv[ni];
                    ssum += tanh_fast(af) * vv[ni];
                }
                ssum += __shfl_xor(ssum, 1, 64);
                ssum += __shfl_xor(ssum, 2, 64);
                ssum += __shfl_xor(ssum, 4, 64);
                ssum += __shfl_xor(ssum, 8, 64);
                if (l15 == 0) sp[w][tl] = ssum;
            }
        }
        __syncthreads();   // sp visible; GEMM reads of As[p] done

        // D: wave0 writes unnormalized attn + accumulates denominator
        if (w == 0) {
            float wv = 0.f;
            if (lane < SR) {
                float sc = sp[0][lane] + sp[1][lane] + sp[2][lane] + sp[3][lane];
                wv = __builtin_amdgcn_exp2f(sc * 1.4426950408889634f)
                     * mask_s[tl0 + lane];
                attn_out[(size_t)b * TK_ + t0b + tl0 + lane] = wv;
            }
            float d = wv;
            d += __shfl_xor(d, 1, 64);  d += __shfl_xor(d, 2, 64);
            d += __shfl_xor(d, 4, 64);  d += __shfl_xor(d, 8, 64);
            d += __shfl_xor(d, 16, 64); d += __shfl_xor(d, 32, 64);
            d_tot += d;
        }

        // E: ctx accumulate in registers (wave w owns rows w*8..w*8+7)
        #pragma unroll
        for (int j = 0; j < 8; ++j) {
            int t = w * 8 + j;
            float sc = sp[0][t] + sp[1][t] + sp[2][t] + sp[3][t];
            float wv = __builtin_amdgcn_exp2f(sc * 1.4426950408889634f)
                       * mask_s[tl0 + t];
            bf16x4 q = *(const bf16x4*)(&As[p][t * 264 + colh]);
            c0 += wv * (float)q[0];
            c1 += wv * (float)q[1];
            c2 += wv * (float)q[2];
            c3 += wv * (float)q[3];
        }

        // F2: write half 2 into the other buffer (latency hid under C/D/E)
        if (s < NS - 1) {
            #pragma unroll
            for (int it = 0; it < 4; ++it) {
                float4 f = hold[it];
                bf16x4 q; q[0]=(bf16_t)f.x; q[1]=(bf16_t)f.y; q[2]=(bf16_t)f.z; q[3]=(bf16_t)f.w;
                *(bf16x4*)(&As[p ^ 1][(16 + it * 4 + w) * 264 + colh]) = q;
            }
        }
        __syncthreads();   // buffer p^1 fully staged; sp free for rewrite
        p ^= 1;
    }

    // final ctx cross-wave reduce (4 partial vectors of 256)
    *(float4*)(&ctxp[w][colh]) = (float4){c0, c1, c2, c3};
    __syncthreads();
    float sctx = ctxp[0][tid] + ctxp[1][tid] + ctxp[2][tid] + ctxp[3][tid];
    ctx_part[((size_t)b * NBX + xb) * H_ + tid] = sctx;

    if (w == 0 && lane == 0) D_part[b * NBX + xb] = d_tot;
}

// ---------------- finalize: reduce partials, write attn / new_cov / c_t ------
__global__ void finalize_kernel(const float* __restrict__ cov,
                                const float* __restrict__ ctx_part,
                                const float* __restrict__ D_part,
                                float* __restrict__ out) {
    int b = blockIdx.y, chunk = blockIdx.x, tid = threadIdx.x;
    int lane = tid & 63;

    // every wave redundantly reduces the 32 denominator partials (no barrier)
    float dv = (lane < NBX) ? D_part[b * NBX + lane] : 0.f;
    dv += __shfl_xor(dv, 1, 64);  dv += __shfl_xor(dv, 2, 64);
    dv += __shfl_xor(dv, 4, 64);  dv += __shfl_xor(dv, 8, 64);
    dv += __shfl_xor(dv, 16, 64); dv += __shfl_xor(dv, 32, 64);
    float invD = 1.0f / dv;

    int idx = chunk * 256 + tid;
    size_t gi = (size_t)b * TK_ + idx;
    float* attn = out + 8192;
    float* ncov = out + 8192 + (size_t)B_ * TK_;
    float a = attn[gi] * invD;
    attn[gi] = a;
    float nc = cov[gi] + a;
    ncov[gi] = fminf(fmaxf(nc, 0.f), 1.f);

    if (chunk == 0) {
        const float* cp = ctx_part + (size_t)b * NBX * H_ + tid;
        float s = 0.f;
        #pragma unroll
        for (int x = 0; x < NBX; ++x) s += cp[(size_t)x * H_];
        out[b * 256 + tid] = s * invD;
    }
}

extern "C" void kernel_launch(void* const* d_in, const int* in_sizes, int n_in,
                              void* d_out, int out_size, void* d_ws, size_t ws_size,
                              hipStream_t stream) {
    const float* s_t_hat = (const float*)d_in[0];
    const float* enc     = (const float*)d_in[1];
    const float* mask    = (const float*)d_in[2];
    const float* cov     = (const float*)d_in[3];
    // d_in[4] = attn_dist_node_to_token: unused by reference
    const float* We      = (const float*)d_in[5];
    const float* Wd      = (const float*)d_in[6];
    const float* bd      = (const float*)d_in[7];
    const float* wc      = (const float*)d_in[8];
    const float* v       = (const float*)d_in[9];
    float* out = (float*)d_out;

    char* ws = (char*)d_ws;
    bf16_t* We_bf    = (bf16_t*)ws;                          // 131072 B
    float*  dec_ws   = (float*)(ws + 131072);                // 32768 B
    float*  D_part   = (float*)(ws + 131072 + 32768);        // 32*32*4 = 4096 B
    float*  ctx_part = (float*)(ws + 131072 + 32768 + 4096); // 32*32*256*4 = 1 MiB

    prep_kernel<<<256, 256, 0, stream>>>(s_t_hat, We, Wd, bd, We_bf, dec_ws);
    attn_main<<<dim3(NBX, 32), 256, 0, stream>>>(enc, mask, cov, wc, v, We_bf,
                                                 dec_ws, ctx_part, D_part, out + 8192);
    finalize_kernel<<<dim3(32, 32), 256, 0, stream>>>(cov, ctx_part, D_part, out);
}

// Round 4
// 505.807 us; speedup vs baseline: 1.1192x; 1.0892x over previous
//
#include <hip/hip_runtime.h>

#define B_  32
#define TK_ 8192
#define H_  256
#define SR  32    // subtile rows
#define NS  8     // subtiles per block
#define NBX 32    // blocks along t (NBX*NS*SR = 8192)

typedef __bf16 bf16_t;
typedef __bf16 bf16x4 __attribute__((ext_vector_type(4)));
typedef __bf16 bf16x8 __attribute__((ext_vector_type(8)));
typedef float  floatx4 __attribute__((ext_vector_type(4)));

__device__ __forceinline__ float tanh_fast(float x) {
    // tanh(x) = 1 - 2/(1+e^{2x});  e^{2x} = exp2(2*log2(e)*x)
    float e = __builtin_amdgcn_exp2f(x * 2.885390081777927f);
    return 1.0f - 2.0f * __builtin_amdgcn_rcpf(e + 1.0f);
}

// ---------------- prep: convert We->bf16, compute dec_fea ---------------------
__global__ void prep_kernel(const float* __restrict__ s_t_hat,
                            const float* __restrict__ We,
                            const float* __restrict__ Wd,
                            const float* __restrict__ bd,
                            bf16_t* __restrict__ We_bf,
                            float* __restrict__ dec_ws) {
    int tid = threadIdx.x, blk = blockIdx.x;
    int gid = blk * 256 + tid;              // grid = 256 blocks -> 65536 threads
    We_bf[gid] = (bf16_t)We[gid];           // H*H = 65536 exactly

    if (blk >= 32 && blk < 160) {           // 32768 threads: 4 per (b,i)
        int idx  = (blk - 32) * 256 + tid;
        int pair = idx >> 2, q = idx & 3;
        int b = pair >> 8, i = pair & 255;
        const float4* sp = (const float4*)(s_t_hat + b * 2 * H_ + q * 128);
        const float4* wp = (const float4*)(Wd + (size_t)i * 2 * H_ + q * 128);
        float sum = 0.f;
        #pragma unroll 8
        for (int ii = 0; ii < 32; ++ii) {
            float4 a = sp[ii], w = wp[ii];
            sum += a.x * w.x + a.y * w.y + a.z * w.z + a.w * w.w;
        }
        sum += __shfl_xor(sum, 1, 64);
        sum += __shfl_xor(sum, 2, 64);
        if (q == 0) dec_ws[pair] = sum + bd[i];
    }
}

// ---------------- main fused pass: 32-row subtiles, LDS double-buffer ---------
// No register-held prefetch: rounds 2/3 proved anything live across the GEMM
// spills (allocator gives only 64 arch VGPRs at 4 blocks/CU with AGPR accs).
// Staging is a self-contained ld->cvt->ds_write burst into the other buffer;
// global loads get hoisted above the MFMAs by the scheduler, the wait lands at
// the mid-barrier. Overlap comes from 4 resident blocks/CU (m114 TLP).
__global__ __launch_bounds__(256, 4) void attn_main(
    const float* __restrict__ enc,
    const float* __restrict__ mask,
    const float* __restrict__ cov,
    const float* __restrict__ wc,
    const float* __restrict__ v,
    const bf16_t* __restrict__ We_bf,
    const float* __restrict__ dec_ws,
    float* __restrict__ ctx_part,   // [B][NBX][H]
    float* __restrict__ D_part,     // [B][NBX]
    float* __restrict__ attn_out) {

    __shared__ __align__(16) bf16_t As[2][SR * 264];   // ping-pong, 33792 B
    __shared__ float sp[4][SR];                        // per-wave score partials
    __shared__ float ctxp[4][256];                     // final ctx reduce
    __shared__ float cov_s[256], mask_s[256];          // whole-block cov/mask

    const int tid  = threadIdx.x;
    const int b    = blockIdx.y;
    const int xb   = blockIdx.x;
    const int lane = tid & 63, w = tid >> 6;
    const int l15  = lane & 15, l4 = lane >> 4;
    const int t0b  = xb * (NS * SR);

    // B-side per-thread constants (L2-resident)
    const int wbase = w * 64;
    float decv[4], wcv[4], vv[4];
    #pragma unroll
    for (int ni = 0; ni < 4; ++ni) {
        int g = wbase + ni * 16 + l15;
        decv[ni] = dec_ws[b * H_ + g];
        wcv[ni]  = wc[g];
        vv[ni]   = v[g];
    }

    const float* encb = enc + ((size_t)b * TK_ + t0b) * H_;
    const int colh = lane * 4;

    // prologue: cov/mask for all 256 rows of this block + stage subtile 0
    cov_s[tid]  = cov[(size_t)b * TK_ + t0b + tid];
    mask_s[tid] = mask[(size_t)b * TK_ + t0b + tid];
    #pragma unroll
    for (int it = 0; it < 8; ++it) {
        int row = it * 4 + w;
        float4 f = *(const float4*)(encb + (size_t)row * H_ + colh);
        bf16x4 q; q[0]=(bf16_t)f.x; q[1]=(bf16_t)f.y; q[2]=(bf16_t)f.z; q[3]=(bf16_t)f.w;
        *(bf16x4*)(&As[0][row * 264 + colh]) = q;
    }
    __syncthreads();

    float c0=0.f, c1=0.f, c2=0.f, c3=0.f;   // ctx acc: rows w*8..w*8+7, h=colh..+3
    float d_tot = 0.f;
    int p = 0;

    for (int s = 0; s < NS; ++s) {
        const int tl0 = s * SR;                 // block-local row base

        // B: GEMM on As[p] — wave w covers g in [w*64, w*64+64)
        floatx4 acc[2][4];
        #pragma unroll
        for (int mi = 0; mi < 2; ++mi)
            #pragma unroll
            for (int ni = 0; ni < 4; ++ni)
                acc[mi][ni] = (floatx4){0.f, 0.f, 0.f, 0.f};

        #pragma unroll
        for (int ks = 0; ks < 8; ++ks) {
            const int k = ks * 32 + l4 * 8;
            bf16x8 a0 = *(const bf16x8*)(&As[p][(     l15) * 264 + k]);
            bf16x8 a1 = *(const bf16x8*)(&As[p][(16 + l15) * 264 + k]);
            bf16x8 bq[4];
            #pragma unroll
            for (int ni = 0; ni < 4; ++ni)
                bq[ni] = *(const bf16x8*)(We_bf + (size_t)(wbase + ni * 16 + l15) * H_ + k);
            #pragma unroll
            for (int ni = 0; ni < 4; ++ni) {
                acc[0][ni] = __builtin_amdgcn_mfma_f32_16x16x32_bf16(a0, bq[ni], acc[0][ni], 0, 0, 0);
                acc[1][ni] = __builtin_amdgcn_mfma_f32_16x16x32_bf16(a1, bq[ni], acc[1][ni], 0, 0, 0);
            }
        }

        // S: stage next subtile into As[p^1] — self-contained, no live-across
        //    values. Scheduler hoists the 8 independent global loads early.
        if (s < NS - 1) {
            const float* nb = encb + (size_t)(s + 1) * SR * H_;
            #pragma unroll
            for (int it = 0; it < 8; ++it) {
                int row = it * 4 + w;
                float4 f = *(const float4*)(nb + (size_t)row * H_ + colh);
                bf16x4 q; q[0]=(bf16_t)f.x; q[1]=(bf16_t)f.y; q[2]=(bf16_t)f.z; q[3]=(bf16_t)f.w;
                *(bf16x4*)(&As[p ^ 1][row * 264 + colh]) = q;
            }
        }

        // C: scores. C-layout: col(g)=lane&15, row(t)=(lane>>4)*4+reg
        #pragma unroll
        for (int mi = 0; mi < 2; ++mi) {
            #pragma unroll
            for (int r = 0; r < 4; ++r) {
                int tl = mi * 16 + l4 * 4 + r;
                float cv = cov_s[tl0 + tl];
                float ssum = 0.f;
                #pragma unroll
                for (int ni = 0; ni < 4; ++ni) {
                    float af = acc[mi][ni][r] + decv[ni] + cv * wcv[ni];
                    ssum += tanh_fast(af) * vv[ni];
                }
                ssum += __shfl_xor(ssum, 1, 64);
                ssum += __shfl_xor(ssum, 2, 64);
                ssum += __shfl_xor(ssum, 4, 64);
                ssum += __shfl_xor(ssum, 8, 64);
                if (l15 == 0) sp[w][tl] = ssum;
            }
        }
        __syncthreads();   // mid: sp visible (As[p^1] also staged by the drain)

        // E (merged D): wave w owns rows w*8..w*8+7 — ctx acc + attn + denom
        #pragma unroll
        for (int j = 0; j < 8; ++j) {
            int t = w * 8 + j;
            float sc = sp[0][t] + sp[1][t] + sp[2][t] + sp[3][t];
            float wv = __builtin_amdgcn_exp2f(sc * 1.4426950408889634f)
                       * mask_s[tl0 + t];
            if (lane == 0) {
                attn_out[(size_t)b * TK_ + t0b + tl0 + t] = wv;
                d_tot += wv;
            }
            bf16x4 q = *(const bf16x4*)(&As[p][t * 264 + colh]);
            c0 += wv * (float)q[0];
            c1 += wv * (float)q[1];
            c2 += wv * (float)q[2];
            c3 += wv * (float)q[3];
        }
        __syncthreads();   // end: sp free for rewrite; As[p] free for re-stage
        p ^= 1;
    }

    // final reduces: d across waves (reuse sp), ctx across waves (ctxp)
    if (lane == 0) sp[w][0] = d_tot;
    *(float4*)(&ctxp[w][colh]) = (float4){c0, c1, c2, c3};
    __syncthreads();
    float sctx = ctxp[0][tid] + ctxp[1][tid] + ctxp[2][tid] + ctxp[3][tid];
    ctx_part[((size_t)b * NBX + xb) * H_ + tid] = sctx;
    if (tid == 0) D_part[b * NBX + xb] = sp[0][0] + sp[1][0] + sp[2][0] + sp[3][0];
}

// ---------------- finalize: reduce partials, write attn / new_cov / c_t ------
__global__ void finalize_kernel(const float* __restrict__ cov,
                                const float* __restrict__ ctx_part,
                                const float* __restrict__ D_part,
                                float* __restrict__ out) {
    int b = blockIdx.y, chunk = blockIdx.x, tid = threadIdx.x;
    int lane = tid & 63;

    // every wave redundantly reduces the 32 denominator partials (no barrier)
    float dv = (lane < NBX) ? D_part[b * NBX + lane] : 0.f;
    dv += __shfl_xor(dv, 1, 64);  dv += __shfl_xor(dv, 2, 64);
    dv += __shfl_xor(dv, 4, 64);  dv += __shfl_xor(dv, 8, 64);
    dv += __shfl_xor(dv, 16, 64); dv += __shfl_xor(dv, 32, 64);
    float invD = 1.0f / dv;

    int idx = chunk * 256 + tid;
    size_t gi = (size_t)b * TK_ + idx;
    float* attn = out + 8192;
    float* ncov = out + 8192 + (size_t)B_ * TK_;
    float a = attn[gi] * invD;
    attn[gi] = a;
    float nc = cov[gi] + a;
    ncov[gi] = fminf(fmaxf(nc, 0.f), 1.f);

    if (chunk == 0) {
        const float* cp = ctx_part + (size_t)b * NBX * H_ + tid;
        float s = 0.f;
        #pragma unroll
        for (int x = 0; x < NBX; ++x) s += cp[(size_t)x * H_];
        out[b * 256 + tid] = s * invD;
    }
}

extern "C" void kernel_launch(void* const* d_in, const int* in_sizes, int n_in,
                              void* d_out, int out_size, void* d_ws, size_t ws_size,
                              hipStream_t stream) {
    const float* s_t_hat = (const float*)d_in[0];
    const float* enc     = (const float*)d_in[1];
    const float* mask    = (const float*)d_in[2];
    const float* cov     = (const float*)d_in[3];
    // d_in[4] = attn_dist_node_to_token: unused by reference
    const float* We      = (const float*)d_in[5];
    const float* Wd      = (const float*)d_in[6];
    const float* bd      = (const float*)d_in[7];
    const float* wc      = (const float*)d_in[8];
    const float* v       = (const float*)d_in[9];
    float* out = (float*)d_out;

    char* ws = (char*)d_ws;
    bf16_t* We_bf    = (bf16_t*)ws;                          // 131072 B
    float*  dec_ws   = (float*)(ws + 131072);                // 32768 B
    float*  D_part   = (float*)(ws + 131072 + 32768);        // 32*32*4 = 4096 B
    float*  ctx_part = (float*)(ws + 131072 + 32768 + 4096); // 32*32*256*4 = 1 MiB

    prep_kernel<<<256, 256, 0, stream>>>(s_t_hat, We, Wd, bd, We_bf, dec_ws);
    attn_main<<<dim3(NBX, 32), 256, 0, stream>>>(enc, mask, cov, wc, v, We_bf,
                                                 dec_ws, ctx_part, D_part, out + 8192);
    finalize_kernel<<<dim3(32, 32), 256, 0, stream>>>(cov, ctx_part, D_part, out);
}